// Round 1
// baseline (100.005 us; speedup 1.0000x reference)
//
#include <hip/hip_runtime.h>
#include <math.h>

// PointWarping: B=4, C=3, N1=N2=8192 fp32.
// out[b,:,n2] = clip(pos2[:,n2] - IDW-avg flow of 3-NN of pos2[:,n2] among (pos1+flow1), +-10)

#define TILE 1024          // DB points staged in LDS per iteration
#define NSEG 8             // DB segments per block (threads 32*s..32*s+31)
#define QPB 32             // queries per block
#define SEGLEN (TILE / NSEG)
#define NTHREADS 256

__global__ __launch_bounds__(NTHREADS) void pointwarp_kernel(
    const float* __restrict__ pos1,
    const float* __restrict__ pos2,
    const float* __restrict__ flow1,
    float* __restrict__ out,
    int N) {
  const int b = blockIdx.y;
  const int qbase = blockIdx.x * QPB;
  const int tid = threadIdx.x;
  const int q = tid & (QPB - 1);  // 0..31: which query this thread serves
  const int s = tid >> 5;         // 0..7: which DB segment this thread scans

  const float* p1 = pos1 + (size_t)b * 3 * N;
  const float* p2 = pos2 + (size_t)b * 3 * N;
  const float* f1 = flow1 + (size_t)b * 3 * N;

  const int qi = qbase + q;
  const float qx = p2[qi];
  const float qy = p2[N + qi];
  const float qz = p2[2 * N + qi];
  // metric m = |k|^2 - 2 q.k   (== d^2 - |q|^2, same ordering per query)
  const float na = -2.0f * qx, nb = -2.0f * qy, nc = -2.0f * qz;

  __shared__ float4 tile[TILE];                 // {kx,ky,kz,|k|^2}
  __shared__ float merge_m[QPB][NSEG][3];
  __shared__ int merge_i[QPB][NSEG][3];

  float m0 = INFINITY, m1 = INFINITY, m2 = INFINITY;
  int i0 = 0, i1 = 0, i2 = 0;

  for (int t = 0; t < N; t += TILE) {
    __syncthreads();
    // cooperative tile load: warped DB points + squared norm
    for (int j = tid; j < TILE; j += NTHREADS) {
      const int g = t + j;
      const float kx = p1[g] + f1[g];
      const float ky = p1[N + g] + f1[N + g];
      const float kz = p1[2 * N + g] + f1[2 * N + g];
      tile[j] = make_float4(kx, ky, kz, kx * kx + ky * ky + kz * kz);
    }
    __syncthreads();

    const int base = s * SEGLEN;
#pragma unroll 4
    for (int j = 0; j < SEGLEN; ++j) {
      const float4 k = tile[base + j];
      const float m = fmaf(na, k.x, fmaf(nb, k.y, fmaf(nc, k.z, k.w)));
      if (m < m2) {  // rare path: maintain sorted top-3 (ascending)
        const int idx = t + base + j;
        if (m < m1) {
          m2 = m1; i2 = i1;
          if (m < m0) {
            m1 = m0; i1 = i0; m0 = m; i0 = idx;
          } else {
            m1 = m; i1 = idx;
          }
        } else {
          m2 = m; i2 = idx;
        }
      }
    }
  }

  merge_m[q][s][0] = m0; merge_m[q][s][1] = m1; merge_m[q][s][2] = m2;
  merge_i[q][s][0] = i0; merge_i[q][s][1] = i1; merge_i[q][s][2] = i2;
  __syncthreads();

  if (tid < QPB) {
    // tid == q here (s == 0), so qx/qy/qz/qi belong to this thread's query.
    float b0 = INFINITY, b1 = INFINITY, b2 = INFINITY;
    int j0 = 0, j1 = 0, j2 = 0;
    for (int ss = 0; ss < NSEG; ++ss) {
      for (int r = 0; r < 3; ++r) {
        const float m = merge_m[tid][ss][r];
        const int idx = merge_i[tid][ss][r];
        // lexicographic (m, idx) to match top_k tie stability
        if (m < b2 || (m == b2 && idx < j2)) {
          if (m < b1 || (m == b1 && idx < j1)) {
            b2 = b1; j2 = j1;
            if (m < b0 || (m == b0 && idx < j0)) {
              b1 = b0; j1 = j0; b0 = m; j0 = idx;
            } else {
              b1 = m; j1 = idx;
            }
          } else {
            b2 = m; j2 = idx;
          }
        }
      }
    }

    // epilogue: recompute exact distances from gathered coords (matches ref)
    const int idxs[3] = {j0, j1, j2};
    float w[3], gfx[3], gfy[3], gfz[3];
    float wsum = 0.0f;
    for (int r = 0; r < 3; ++r) {
      const int idx = idxs[r];
      const float fx = f1[idx], fy = f1[N + idx], fz = f1[2 * N + idx];
      const float kx = p1[idx] + fx;
      const float ky = p1[N + idx] + fy;
      const float kz = p1[2 * N + idx] + fz;
      const float dx = kx - qx, dy = ky - qy, dz = kz - qz;
      float d = sqrtf(dx * dx + dy * dy + dz * dz);
      d = fmaxf(d, 1e-10f);
      const float inv = 1.0f / d;
      w[r] = inv; wsum += inv;
      gfx[r] = fx; gfy[r] = fy; gfz[r] = fz;
    }
    const float invw = 1.0f / wsum;
    float ox = 0.0f, oy = 0.0f, oz = 0.0f;
    for (int r = 0; r < 3; ++r) {
      const float ww = w[r] * invw;
      ox = fmaf(ww, gfx[r], ox);
      oy = fmaf(ww, gfy[r], oy);
      oz = fmaf(ww, gfz[r], oz);
    }
    ox = qx - ox; oy = qy - oy; oz = qz - oz;
    ox = fminf(fmaxf(ox, -10.0f), 10.0f);
    oy = fminf(fmaxf(oy, -10.0f), 10.0f);
    oz = fminf(fmaxf(oz, -10.0f), 10.0f);
    float* o = out + (size_t)b * 3 * N;
    o[qi] = ox;
    o[N + qi] = oy;
    o[2 * N + qi] = oz;
  }
}

extern "C" void kernel_launch(void* const* d_in, const int* in_sizes, int n_in,
                              void* d_out, int out_size, void* d_ws, size_t ws_size,
                              hipStream_t stream) {
  const float* pos1 = (const float*)d_in[0];
  const float* pos2 = (const float*)d_in[1];
  const float* flow1 = (const float*)d_in[2];
  float* out = (float*)d_out;

  const int B = 4;
  const int N = in_sizes[0] / (B * 3);  // 8192

  dim3 grid(N / QPB, B);
  dim3 block(NTHREADS);
  pointwarp_kernel<<<grid, block, 0, stream>>>(pos1, pos2, flow1, out, N);
}